// Round 13
// baseline (30.707 us; speedup 1.0000x reference)
//
#include <hip/hip_runtime.h>

#define PN 131072
#define PH 1024
#define G 128
#define GPTS (G * G)
#define PPB 16                 // grid points per block (K1)
#define NBLK1 (GPTS / PPB)     // 1024 blocks
#define GLO   (-5.0f)
#define GSTEP (10.0f / 127.0f)
#define GINV  (127.0f / 10.0f)
#define XMAX  4.9f
// SC = 2*log2(e); fold into the point coords so zs = SC*z with raw weights.
#define SCGSTEP (2.8853900817779268f * GSTEP)
#define SCGLO   (2.8853900817779268f * GLO)

// Catmull-Rom weights for t in [0,1)
static __device__ __forceinline__ void cr_w(float t, float w[4]) {
    w[0] = t * (-0.5f + t * (1.0f - 0.5f * t));
    w[1] = 1.0f + t * t * (-2.5f + 1.5f * t);
    w[2] = t * (0.5f + t * (2.0f - 1.5f * t));
    w[3] = t * t * (-0.5f + 0.5f * t);
}

// ===== K1: table eval — params in REGISTERS, loop over points ===============
// 1024 blocks x 256 thr (4 waves). Wave w owns h-chunk [w*256, w*256+256).
// Lane l owns 4 h: h0 = w*256 + 4l  (2 pairs). All consts live in VGPRs.
// Per point: pure VALU/trans compute + shfl butterfly; LDS only for the
// 4-wave merge of 16 points at block end.
__global__ __launch_bounds__(256) void eval_kernel(const float4* __restrict__ W1f4,
                                                   const float4* __restrict__ b1f4,
                                                   const float4* __restrict__ w2f4,
                                                   const float* __restrict__ b2p,
                                                   float4* __restrict__ gridout) {
    const int tid = threadIdx.x;
    const int lane = tid & 63, wv = tid >> 6;      // 4 waves
    const int bid = blockIdx.x;
    const float SC = 2.8853900817779268f;

    // ---- one-time per-lane parameter load (coalesced) + in-register prep ----
    const float4 Wa = W1f4[wv * 128 + 2 * lane];       // w10,w11 of h0,h0+1
    const float4 Wb = W1f4[wv * 128 + 2 * lane + 1];   // w10,w11 of h0+2,h0+3
    const float4 Bv = b1f4[wv * 64 + lane];            // b1 of h0..h0+3
    const float4 Vv = w2f4[wv * 64 + lane];            // w2 of h0..h0+3

    const float b1sa = Bv.x * SC, b1sb = Bv.y * SC;
    const float b1sc = Bv.z * SC, b1sd = Bv.w * SC;
    const float w2a = Vv.x, w2b = Vv.y, w2c = Vv.z, w2d = Vv.w;
    const float c1a = 4.0f * Wa.x * w2a, c2a = 4.0f * Wa.y * w2a, c3a = Wa.y * c2a;
    const float c1b = 4.0f * Wa.z * w2b, c2b = 4.0f * Wa.w * w2b, c3b = Wa.w * c2b;
    const float c1c = 4.0f * Wb.x * w2c, c2c = 4.0f * Wb.y * w2c, c3c = Wb.y * c2c;
    const float c1d = 4.0f * Wb.z * w2d, c2d = 4.0f * Wb.w * w2d, c3d = Wb.w * c2d;

    // sum of w2 over this wave's chunk (once)
    float sw2 = w2a + w2b + w2c + w2d;
    #pragma unroll
    for (int m = 32; m >= 1; m >>= 1) sw2 += __shfl_xor(sw2, m, 64);

    __shared__ float sw2s[4];
    __shared__ float4 ptres[PPB][4];
    if (lane == 0) sw2s[wv] = sw2;

    #pragma unroll 1
    for (int pt = 0; pt < PPB; ++pt) {
        const int p  = bid * PPB + pt;
        const int ix = p & (G - 1);
        const int iy = p >> 7;
        const float x0s = __builtin_fmaf((float)ix, SCGSTEP, SCGLO);
        const float x1s = __builtin_fmaf((float)iy, SCGSTEP, SCGLO);

        float aR = 0.f, a1 = 0.f, a2 = 0.f, aD = 0.f;

        // ---- pair 1: h0, h0+1 ----
        {
            float zsa = __builtin_fmaf(x0s, Wa.x, __builtin_fmaf(x1s, Wa.y, b1sa));
            float zsb = __builtin_fmaf(x0s, Wa.z, __builtin_fmaf(x1s, Wa.w, b1sb));
            zsa = fminf(zsa, 40.0f);
            zsb = fminf(zsb, 40.0f);
            const float ea = __builtin_amdgcn_exp2f(zsa);
            const float eb = __builtin_amdgcn_exp2f(zsb);
            const float da = ea + 1.0f, db = eb + 1.0f;
            const float rab = __builtin_amdgcn_rcpf(da * db);
            const float ra = rab * db, rb = rab * da;      // 1/(1+e^{2z})
            const float ua = __builtin_fmaf(-ra, ra, ra);  // r - r^2
            const float ub = __builtin_fmaf(-rb, rb, rb);
            const float rua = ra * ua, rub = rb * ub;
            const float tua = __builtin_fmaf(-2.0f, rua, ua);  // t*u
            const float tub = __builtin_fmaf(-2.0f, rub, ub);
            aR = __builtin_fmaf(ra, w2a, aR);
            aR = __builtin_fmaf(rb, w2b, aR);
            a1 = __builtin_fmaf(ua, c1a, a1);
            a1 = __builtin_fmaf(ub, c1b, a1);
            a2 = __builtin_fmaf(ua, c2a, a2);
            a2 = __builtin_fmaf(ub, c2b, a2);
            aD = __builtin_fmaf(tua, c3a, aD);
            aD = __builtin_fmaf(tub, c3b, aD);
        }
        // ---- pair 2: h0+2, h0+3 ----
        {
            float zsa = __builtin_fmaf(x0s, Wb.x, __builtin_fmaf(x1s, Wb.y, b1sc));
            float zsb = __builtin_fmaf(x0s, Wb.z, __builtin_fmaf(x1s, Wb.w, b1sd));
            zsa = fminf(zsa, 40.0f);
            zsb = fminf(zsb, 40.0f);
            const float ea = __builtin_amdgcn_exp2f(zsa);
            const float eb = __builtin_amdgcn_exp2f(zsb);
            const float da = ea + 1.0f, db = eb + 1.0f;
            const float rab = __builtin_amdgcn_rcpf(da * db);
            const float ra = rab * db, rb = rab * da;
            const float ua = __builtin_fmaf(-ra, ra, ra);
            const float ub = __builtin_fmaf(-rb, rb, rb);
            const float rua = ra * ua, rub = rb * ub;
            const float tua = __builtin_fmaf(-2.0f, rua, ua);
            const float tub = __builtin_fmaf(-2.0f, rub, ub);
            aR = __builtin_fmaf(ra, w2c, aR);
            aR = __builtin_fmaf(rb, w2d, aR);
            a1 = __builtin_fmaf(ua, c1c, a1);
            a1 = __builtin_fmaf(ub, c1d, a1);
            a2 = __builtin_fmaf(ua, c2c, a2);
            a2 = __builtin_fmaf(ub, c2d, a2);
            aD = __builtin_fmaf(tua, c3c, aD);
            aD = __builtin_fmaf(tub, c3d, aD);
        }

        // butterfly across the wave
        #pragma unroll
        for (int m = 32; m >= 1; m >>= 1) {
            aR += __shfl_xor(aR, m, 64);
            a1 += __shfl_xor(a1, m, 64);
            a2 += __shfl_xor(a2, m, 64);
            aD += __shfl_xor(aD, m, 64);
        }
        if (lane == pt) ptres[pt][wv] = make_float4(aR, a1, a2, aD);
    }

    __syncthreads();
    if (tid < PPB) {
        float4 s = ptres[tid][0];
        #pragma unroll
        for (int w = 1; w < 4; ++w) {
            const float4 o = ptres[tid][w];
            s.x += o.x; s.y += o.y; s.z += o.z; s.w += o.w;
        }
        const float sw2all = sw2s[0] + sw2s[1] + sw2s[2] + sw2s[3];
        // f = sum w2*(1-2r)+b2 ; ft = sum u*c1 ; fx = sum u*c2 ; fxx = -2*sum tu*c3
        const float f   = sw2all + b2p[0] - 2.0f * s.x;
        const float ft  = s.y;
        const float fx  = s.z;
        const float fxx = -2.0f * s.w;
        gridout[bid * PPB + tid] = make_float4(f, ft, fx, fxx);
    }
}

// ===== K2: bicubic interp, 2 threads per row + cooperative fallback =========
__global__ __launch_bounds__(256) void interp_kernel(const float2* __restrict__ x2,
                                                     const float4* __restrict__ grid,
                                                     const float* __restrict__ W1,
                                                     const float* __restrict__ b1,
                                                     const float* __restrict__ w2,
                                                     const float* __restrict__ b2p,
                                                     float* __restrict__ out) {
    const int g = blockIdx.x * 256 + threadIdx.x;
    const int row = g >> 1;
    const int half = g & 1;
    const float2 xv = x2[row];

    float u = (xv.x - GLO) * GINV;
    float v = (xv.y - GLO) * GINV;
    u = fminf(fmaxf(u, 0.0f), (float)(G - 1) - 1e-3f);
    v = fminf(fmaxf(v, 0.0f), (float)(G - 1) - 1e-3f);
    int iu = (int)u;  iu = iu > G - 2 ? G - 2 : iu;
    int iv = (int)v;  iv = iv > G - 2 ? G - 2 : iv;
    const float fu = u - (float)iu;
    const float fv = v - (float)iv;

    float wu[4], wv_[4];
    cr_w(fu, wu);
    cr_w(fv, wv_);

    const int ju0 = iu - 1 < 0 ? 0 : iu - 1;
    const int ju3 = iu + 2 > G - 1 ? G - 1 : iu + 2;
    const int jv0 = iv - 1 < 0 ? 0 : iv - 1;
    const int jv3 = iv + 2 > G - 1 ? G - 1 : iv + 2;
    const int rowsIdx[4] = { jv0 * G, iv * G, (iv + 1) * G, jv3 * G };

    float af = 0.f, at = 0.f, ax = 0.f, axx = 0.f;
    #pragma unroll
    for (int rr = 0; rr < 2; ++rr) {
        const int r = 2 * half + rr;          // this thread's 2 stencil rows
        const int base = rowsIdx[r];
        const float4 g0 = grid[base + ju0];
        const float4 g1 = grid[base + iu];
        const float4 g2 = grid[base + iu + 1];
        const float4 g3 = grid[base + ju3];
        const float rf  = wu[0] * g0.x + wu[1] * g1.x + wu[2] * g2.x + wu[3] * g3.x;
        const float rt  = wu[0] * g0.y + wu[1] * g1.y + wu[2] * g2.y + wu[3] * g3.y;
        const float rx  = wu[0] * g0.z + wu[1] * g1.z + wu[2] * g2.z + wu[3] * g3.z;
        const float rxx = wu[0] * g0.w + wu[1] * g1.w + wu[2] * g2.w + wu[3] * g3.w;
        af  = __builtin_fmaf(wv_[r], rf,  af);
        at  = __builtin_fmaf(wv_[r], rt,  at);
        ax  = __builtin_fmaf(wv_[r], rx,  ax);
        axx = __builtin_fmaf(wv_[r], rxx, axx);
    }
    af  += __shfl_xor(af,  1, 64);
    at  += __shfl_xor(at,  1, 64);
    ax  += __shfl_xor(ax,  1, 64);
    axx += __shfl_xor(axx, 1, 64);

    // fallback: exact direct eval for out-of-range rows (cooperative, rare)
    const bool outl = ((fabsf(xv.x) > XMAX) || (fabsf(xv.y) > XMAX)) && (half == 0);
    unsigned long long mball = __ballot(outl);
    if (mball) {
        const int lane = threadIdx.x & 63;
        const float SC = 2.8853900817779268f;
        const float b2v = b2p[0];
        while (mball) {
            const int l = (int)__ffsll((unsigned long long)mball) - 1;
            mball &= mball - 1;
            const float fx0 = __shfl(xv.x, l, 64);
            const float fx1 = __shfl(xv.y, l, 64);
            float s_f = 0.f, s1 = 0.f, s2 = 0.f, s3 = 0.f, s4 = 0.f;
            for (int k = 0; k < 16; ++k) {
                const int h = lane * 16 + k;
                const float w10 = W1[2 * h], w11 = W1[2 * h + 1];
                const float b1h = b1[h], w2h = w2[h];
                float zs = SC * __builtin_fmaf(fx0, w10, __builtin_fmaf(fx1, w11, b1h));
                zs = fminf(zs, 40.0f);
                const float e = __builtin_amdgcn_exp2f(zs);
                const float r = __builtin_amdgcn_rcpf(e + 1.0f);
                const float t = __builtin_fmaf(-2.0f, r, 1.0f);
                const float uq = __builtin_fmaf(-r, r, r);
                const float ru = r * uq;
                const float c1 = w10 * w2h, c2 = w11 * w2h, c3 = w11 * c2;
                s_f += t * w2h;
                s1 = __builtin_fmaf(uq, c1, s1);
                s2 = __builtin_fmaf(uq, c2, s2);
                s3 = __builtin_fmaf(uq, c3, s3);
                s4 = __builtin_fmaf(ru, c3, s4);
            }
            #pragma unroll
            for (int m = 32; m >= 1; m >>= 1) {
                s_f += __shfl_xor(s_f, m, 64);
                s1  += __shfl_xor(s1,  m, 64);
                s2  += __shfl_xor(s2,  m, 64);
                s3  += __shfl_xor(s3,  m, 64);
                s4  += __shfl_xor(s4,  m, 64);
            }
            if (lane == l) {
                af  = s_f + b2v;
                at  = 4.0f * s1;
                ax  = 4.0f * s2;
                axx = -8.0f * (s3 - 2.0f * s4);
            }
        }
    }

    if (half == 0) {
        const float x1 = xv.y;
        const float pde = __builtin_fmaf(0.5f * x1, x1, at)
                        + 0.5f * axx
                        + 0.5f * x1 * ax
                        - 0.069444444444444445f * ax * ax;
        out[row] = af;
        out[PN + row] = pde;
    }
}

extern "C" void kernel_launch(void* const* d_in, const int* in_sizes, int n_in,
                              void* d_out, int out_size, void* d_ws, size_t ws_size,
                              hipStream_t stream) {
    const float* x  = (const float*)d_in[0];
    const float* W1 = (const float*)d_in[1];
    const float* b1 = (const float*)d_in[2];
    const float* w2 = (const float*)d_in[3];
    const float* b2 = (const float*)d_in[4];
    float* out = (float*)d_out;
    float4* grid = (float4*)d_ws;      // G*G float4 = 256 KiB

    eval_kernel<<<NBLK1, 256, 0, stream>>>((const float4*)W1, (const float4*)b1,
                                           (const float4*)w2, b2, grid);
    interp_kernel<<<PN * 2 / 256, 256, 0, stream>>>((const float2*)x, grid,
                                                    W1, b1, w2, b2, out);
}

// Round 14
// 22.161 us; speedup vs baseline: 1.3856x; 1.3856x over previous
//
#include <hip/hip_runtime.h>

#define PN 131072
#define PH 1024
#define G 128
#define GPTS (G * G)
#define GLO   (-5.0f)
#define GSTEP (10.0f / 127.0f)
#define GINV  (127.0f / 10.0f)
#define XMAX  4.9f            // beyond this -> direct-eval fallback
#define SCF   2.8853900817779268f          // 2*log2(e)
#define INV_SC  0.34657359027997264f       // 1/SC
#define INV_SC2 0.12011325347955035f       // 1/SC^2

// Catmull-Rom weights for t in [0,1)
static __device__ __forceinline__ void cr_w(float t, float w[4]) {
    w[0] = t * (-0.5f + t * (1.0f - 0.5f * t));
    w[1] = 1.0f + t * t * (-2.5f + 1.5f * t);
    w[2] = t * (0.5f + t * (2.0f - 1.5f * t));
    w[3] = t * t * (-0.5f + 0.5f * t);
}

// ===== K1: grid_eval; ONE float4 per h in LDS (halved DS-pipe traffic) ======
// 256 blocks x 1024 threads; lane = grid point (64/block), 16 waves split H
// into 16 wave-uniform 64-h chunks. Per pair: 2 ds_read_b128 (was 4).
__global__ __launch_bounds__(1024) void grid_eval_kernel(const float* __restrict__ W1,
                                                         const float* __restrict__ b1,
                                                         const float* __restrict__ w2,
                                                         const float* __restrict__ b2p,
                                                         float4* __restrict__ gridout) {
    __shared__ float4 pk[PH];         // {SC*w10, SC*w11, SC*b1, w2}  16 KiB
    __shared__ float4 red[16][64];
    __shared__ float sred[16];
    __shared__ float sfb;

    const int bid = blockIdx.x, tid = threadIdx.x;
    const int lane = tid & 63, wv = tid >> 6;
    const int wvu = __builtin_amdgcn_readfirstlane(wv);

    // ---- prep: thread t handles h = t ----
    {
        const int h = tid;
        const float2 Wp = reinterpret_cast<const float2*>(W1)[h];
        const float w2h = w2[h];
        pk[h] = make_float4(Wp.x * SCF, Wp.y * SCF, b1[h] * SCF, w2h);
        float ws = w2h;
        #pragma unroll
        for (int m = 32; m >= 1; m >>= 1) ws += __shfl_xor(ws, m, 64);
        if (lane == 0) sred[wv] = ws;
    }
    __syncthreads();
    if (tid == 0) {
        float s = 0.f;
        #pragma unroll
        for (int w = 0; w < 16; ++w) s += sred[w];
        sfb = s + b2p[0];             // sum(w2) + b2
    }
    __syncthreads();

    const int p  = bid * 64 + lane;
    const int ix = p & (G - 1);
    const int iy = p >> 7;
    const float x0 = __builtin_fmaf((float)ix, GSTEP, GLO);
    const float x1 = __builtin_fmaf((float)iy, GSTEP, GLO);

    const float4* __restrict__ pA = &pk[wvu * 64];

    float aR = 0.f, a1 = 0.f, a2 = 0.f, aD = 0.f;

    #pragma unroll 4
    for (int j = 0; j < 32; ++j) {
        const float4 Pa = pA[2 * j];
        const float4 Pb = pA[2 * j + 1];

        float zsa = __builtin_fmaf(x0, Pa.x, __builtin_fmaf(x1, Pa.y, Pa.z));
        float zsb = __builtin_fmaf(x0, Pb.x, __builtin_fmaf(x1, Pb.y, Pb.z));
        zsa = fminf(zsa, 40.0f);
        zsb = fminf(zsb, 40.0f);
        const float ea = __builtin_amdgcn_exp2f(zsa);       // e^{2z}
        const float eb = __builtin_amdgcn_exp2f(zsb);
        const float da = ea + 1.0f, db = eb + 1.0f;
        const float rab = __builtin_amdgcn_rcpf(da * db);   // shared rcp
        const float ra = rab * db, rb = rab * da;           // 1/(1+e^{2z})
        const float ua = __builtin_fmaf(-ra, ra, ra);       // r - r^2
        const float ub = __builtin_fmaf(-rb, rb, rb);
        const float rua = ra * ua, rub = rb * ub;
        const float tua = __builtin_fmaf(-2.0f, rua, ua);   // t*u
        const float tub = __builtin_fmaf(-2.0f, rub, ub);

        const float uw2a = ua * Pa.w,  uw2b = ub * Pb.w;    // u*w2
        const float tw2a = tua * Pa.w, tw2b = tub * Pb.w;   // t*u*w2

        aR = __builtin_fmaf(ra, Pa.w, aR);
        aR = __builtin_fmaf(rb, Pb.w, aR);
        a1 = __builtin_fmaf(uw2a, Pa.x, a1);                // * SC*w10
        a1 = __builtin_fmaf(uw2b, Pb.x, a1);
        a2 = __builtin_fmaf(uw2a, Pa.y, a2);                // * SC*w11
        a2 = __builtin_fmaf(uw2b, Pb.y, a2);
        aD = __builtin_fmaf(tw2a * Pa.y, Pa.y, aD);         // * (SC*w11)^2
        aD = __builtin_fmaf(tw2b * Pb.y, Pb.y, aD);
    }

    red[wv][lane] = make_float4(aR, a1, a2, aD);
    __syncthreads();
    if (tid < 64) {
        float4 s = red[0][tid];
        #pragma unroll
        for (int w = 1; w < 16; ++w) {
            const float4 o = red[w][tid];
            s.x += o.x; s.y += o.y; s.z += o.z; s.w += o.w;
        }
        // f = sum w2*(1-2r)+b2 ; ft = 4/SC * a1 ; fx = 4/SC * a2 ;
        // fxx = -8/SC^2 * aD
        const float f   = sfb - 2.0f * s.x;
        const float ft  = 4.0f * INV_SC * s.y;
        const float fx  = 4.0f * INV_SC * s.z;
        const float fxx = -8.0f * INV_SC2 * s.w;
        gridout[bid * 64 + tid] = make_float4(f, ft, fx, fxx);
    }
}

// ===== K2: bicubic interp + wave-cooperative direct fallback (R11 shape) ====
__global__ __launch_bounds__(256) void interp_kernel(const float2* __restrict__ x2,
                                                     const float4* __restrict__ grid,
                                                     const float* __restrict__ W1,
                                                     const float* __restrict__ b1,
                                                     const float* __restrict__ w2,
                                                     const float* __restrict__ b2p,
                                                     float* __restrict__ out) {
    const int i = blockIdx.x * 256 + threadIdx.x;
    const float2 xv = x2[i];

    float u = (xv.x - GLO) * GINV;
    float v = (xv.y - GLO) * GINV;
    u = fminf(fmaxf(u, 0.0f), (float)(G - 1) - 1e-3f);
    v = fminf(fmaxf(v, 0.0f), (float)(G - 1) - 1e-3f);
    int iu = (int)u;  iu = iu > G - 2 ? G - 2 : iu;
    int iv = (int)v;  iv = iv > G - 2 ? G - 2 : iv;
    const float fu = u - (float)iu;
    const float fv = v - (float)iv;

    float wu[4], wv_[4];
    cr_w(fu, wu);
    cr_w(fv, wv_);

    const int ju0 = iu - 1 < 0 ? 0 : iu - 1;
    const int ju3 = iu + 2 > G - 1 ? G - 1 : iu + 2;
    const int jv0 = iv - 1 < 0 ? 0 : iv - 1;
    const int jv3 = iv + 2 > G - 1 ? G - 1 : iv + 2;
    const int rows[4] = { jv0 * G, iv * G, (iv + 1) * G, jv3 * G };

    float af = 0.f, at = 0.f, ax = 0.f, axx = 0.f;
    #pragma unroll
    for (int r = 0; r < 4; ++r) {
        const int base = rows[r];
        const float4 g0 = grid[base + ju0];
        const float4 g1 = grid[base + iu];
        const float4 g2 = grid[base + iu + 1];
        const float4 g3 = grid[base + ju3];
        const float rf  = wu[0] * g0.x + wu[1] * g1.x + wu[2] * g2.x + wu[3] * g3.x;
        const float rt  = wu[0] * g0.y + wu[1] * g1.y + wu[2] * g2.y + wu[3] * g3.y;
        const float rx  = wu[0] * g0.z + wu[1] * g1.z + wu[2] * g2.z + wu[3] * g3.z;
        const float rxx = wu[0] * g0.w + wu[1] * g1.w + wu[2] * g2.w + wu[3] * g3.w;
        af  = __builtin_fmaf(wv_[r], rf,  af);
        at  = __builtin_fmaf(wv_[r], rt,  at);
        ax  = __builtin_fmaf(wv_[r], rx,  ax);
        axx = __builtin_fmaf(wv_[r], rxx, axx);
    }

    const bool outl = (fabsf(xv.x) > XMAX) || (fabsf(xv.y) > XMAX);
    unsigned long long mball = __ballot(outl);
    if (mball) {
        const int lane = threadIdx.x & 63;
        const float b2v = b2p[0];
        while (mball) {
            const int l = (int)__ffsll((unsigned long long)mball) - 1;
            mball &= mball - 1;
            const float fx0 = __shfl(xv.x, l, 64);
            const float fx1 = __shfl(xv.y, l, 64);
            float s_f = 0.f, s1 = 0.f, s2 = 0.f, s3 = 0.f, s4 = 0.f;
            for (int k = 0; k < 16; ++k) {
                const int h = lane * 16 + k;
                const float w10 = W1[2 * h], w11 = W1[2 * h + 1];
                const float b1h = b1[h], w2h = w2[h];
                float zs = SCF * __builtin_fmaf(fx0, w10, __builtin_fmaf(fx1, w11, b1h));
                zs = fminf(zs, 40.0f);
                const float e = __builtin_amdgcn_exp2f(zs);
                const float r = __builtin_amdgcn_rcpf(e + 1.0f);
                const float t = __builtin_fmaf(-2.0f, r, 1.0f);
                const float uq = __builtin_fmaf(-r, r, r);
                const float ru = r * uq;
                const float c1 = w10 * w2h, c2 = w11 * w2h, c3 = w11 * c2;
                s_f += t * w2h;
                s1 = __builtin_fmaf(uq, c1, s1);
                s2 = __builtin_fmaf(uq, c2, s2);
                s3 = __builtin_fmaf(uq, c3, s3);
                s4 = __builtin_fmaf(ru, c3, s4);
            }
            #pragma unroll
            for (int m = 32; m >= 1; m >>= 1) {
                s_f += __shfl_xor(s_f, m, 64);
                s1  += __shfl_xor(s1,  m, 64);
                s2  += __shfl_xor(s2,  m, 64);
                s3  += __shfl_xor(s3,  m, 64);
                s4  += __shfl_xor(s4,  m, 64);
            }
            if (lane == l) {
                af  = s_f + b2v;
                at  = 4.0f * s1;
                ax  = 4.0f * s2;
                axx = -8.0f * (s3 - 2.0f * s4);
            }
        }
    }

    const float x1 = xv.y;
    const float pde = __builtin_fmaf(0.5f * x1, x1, at)
                    + 0.5f * axx
                    + 0.5f * x1 * ax
                    - 0.069444444444444445f * ax * ax;
    out[i] = af;
    out[PN + i] = pde;
}

extern "C" void kernel_launch(void* const* d_in, const int* in_sizes, int n_in,
                              void* d_out, int out_size, void* d_ws, size_t ws_size,
                              hipStream_t stream) {
    const float* x  = (const float*)d_in[0];
    const float* W1 = (const float*)d_in[1];
    const float* b1 = (const float*)d_in[2];
    const float* w2 = (const float*)d_in[3];
    const float* b2 = (const float*)d_in[4];
    float* out = (float*)d_out;
    float4* grid = (float4*)d_ws;      // G*G float4 = 256 KiB

    grid_eval_kernel<<<GPTS / 64, 1024, 0, stream>>>(W1, b1, w2, b2, grid);
    interp_kernel<<<PN / 256, 256, 0, stream>>>((const float2*)x, grid,
                                                W1, b1, w2, b2, out);
}

// Round 15
// 21.704 us; speedup vs baseline: 1.4148x; 1.0211x over previous
//
#include <hip/hip_runtime.h>

#define PN 131072
#define PH 1024
#define G 128
#define GPTS (G * G)
#define GLO   (-5.0f)
#define GSTEP (10.0f / 127.0f)
#define GINV  (127.0f / 10.0f)
#define XMAX  4.9f            // beyond this -> direct-eval fallback
#define SCF   2.8853900817779268f          // 2*log2(e)
#define INV_SC  0.34657359027997264f       // 1/SC
#define INV_SC2 0.12011325347955035f       // 1/SC^2

// Catmull-Rom weights for t in [0,1)
static __device__ __forceinline__ void cr_w(float t, float w[4]) {
    w[0] = t * (-0.5f + t * (1.0f - 0.5f * t));
    w[1] = 1.0f + t * t * (-2.5f + 1.5f * t);
    w[2] = t * (0.5f + t * (2.0f - 1.5f * t));
    w[3] = t * t * (-0.5f + 0.5f * t);
}

// ===== K1: grid_eval; identical to R14 (validated 22.2us total) =============
__global__ __launch_bounds__(1024) void grid_eval_kernel(const float* __restrict__ W1,
                                                         const float* __restrict__ b1,
                                                         const float* __restrict__ w2,
                                                         const float* __restrict__ b2p,
                                                         float4* __restrict__ gridout) {
    __shared__ float4 pk[PH];         // {SC*w10, SC*w11, SC*b1, w2}  16 KiB
    __shared__ float4 red[16][64];
    __shared__ float sred[16];
    __shared__ float sfb;

    const int bid = blockIdx.x, tid = threadIdx.x;
    const int lane = tid & 63, wv = tid >> 6;
    const int wvu = __builtin_amdgcn_readfirstlane(wv);

    {
        const int h = tid;
        const float2 Wp = reinterpret_cast<const float2*>(W1)[h];
        const float w2h = w2[h];
        pk[h] = make_float4(Wp.x * SCF, Wp.y * SCF, b1[h] * SCF, w2h);
        float ws = w2h;
        #pragma unroll
        for (int m = 32; m >= 1; m >>= 1) ws += __shfl_xor(ws, m, 64);
        if (lane == 0) sred[wv] = ws;
    }
    __syncthreads();
    if (tid == 0) {
        float s = 0.f;
        #pragma unroll
        for (int w = 0; w < 16; ++w) s += sred[w];
        sfb = s + b2p[0];             // sum(w2) + b2
    }
    __syncthreads();

    const int p  = bid * 64 + lane;
    const int ix = p & (G - 1);
    const int iy = p >> 7;
    const float x0 = __builtin_fmaf((float)ix, GSTEP, GLO);
    const float x1 = __builtin_fmaf((float)iy, GSTEP, GLO);

    const float4* __restrict__ pA = &pk[wvu * 64];

    float aR = 0.f, a1 = 0.f, a2 = 0.f, aD = 0.f;

    #pragma unroll 4
    for (int j = 0; j < 32; ++j) {
        const float4 Pa = pA[2 * j];
        const float4 Pb = pA[2 * j + 1];

        float zsa = __builtin_fmaf(x0, Pa.x, __builtin_fmaf(x1, Pa.y, Pa.z));
        float zsb = __builtin_fmaf(x0, Pb.x, __builtin_fmaf(x1, Pb.y, Pb.z));
        zsa = fminf(zsa, 40.0f);
        zsb = fminf(zsb, 40.0f);
        const float ea = __builtin_amdgcn_exp2f(zsa);       // e^{2z}
        const float eb = __builtin_amdgcn_exp2f(zsb);
        const float da = ea + 1.0f, db = eb + 1.0f;
        const float rab = __builtin_amdgcn_rcpf(da * db);   // shared rcp
        const float ra = rab * db, rb = rab * da;           // 1/(1+e^{2z})
        const float ua = __builtin_fmaf(-ra, ra, ra);       // r - r^2
        const float ub = __builtin_fmaf(-rb, rb, rb);
        const float rua = ra * ua, rub = rb * ub;
        const float tua = __builtin_fmaf(-2.0f, rua, ua);   // t*u
        const float tub = __builtin_fmaf(-2.0f, rub, ub);

        const float uw2a = ua * Pa.w,  uw2b = ub * Pb.w;    // u*w2
        const float tw2a = tua * Pa.w, tw2b = tub * Pb.w;   // t*u*w2

        aR = __builtin_fmaf(ra, Pa.w, aR);
        aR = __builtin_fmaf(rb, Pb.w, aR);
        a1 = __builtin_fmaf(uw2a, Pa.x, a1);                // * SC*w10
        a1 = __builtin_fmaf(uw2b, Pb.x, a1);
        a2 = __builtin_fmaf(uw2a, Pa.y, a2);                // * SC*w11
        a2 = __builtin_fmaf(uw2b, Pb.y, a2);
        aD = __builtin_fmaf(tw2a * Pa.y, Pa.y, aD);         // * (SC*w11)^2
        aD = __builtin_fmaf(tw2b * Pb.y, Pb.y, aD);
    }

    red[wv][lane] = make_float4(aR, a1, a2, aD);
    __syncthreads();
    if (tid < 64) {
        float4 s = red[0][tid];
        #pragma unroll
        for (int w = 1; w < 16; ++w) {
            const float4 o = red[w][tid];
            s.x += o.x; s.y += o.y; s.z += o.z; s.w += o.w;
        }
        const float f   = sfb - 2.0f * s.x;
        const float ft  = 4.0f * INV_SC * s.y;
        const float fx  = 4.0f * INV_SC * s.z;
        const float fxx = -8.0f * INV_SC2 * s.w;
        gridout[bid * 64 + tid] = make_float4(f, ft, fx, fxx);
    }
}

// ===== K2: bicubic interp, 2 threads/row (half gather chain, 2x waves) ======
__global__ __launch_bounds__(256) void interp_kernel(const float2* __restrict__ x2,
                                                     const float4* __restrict__ grid,
                                                     const float* __restrict__ W1,
                                                     const float* __restrict__ b1,
                                                     const float* __restrict__ w2,
                                                     const float* __restrict__ b2p,
                                                     float* __restrict__ out) {
    const int g = blockIdx.x * 256 + threadIdx.x;
    const int row = g >> 1;
    const int half = g & 1;
    const float2 xv = x2[row];

    float u = (xv.x - GLO) * GINV;
    float v = (xv.y - GLO) * GINV;
    u = fminf(fmaxf(u, 0.0f), (float)(G - 1) - 1e-3f);
    v = fminf(fmaxf(v, 0.0f), (float)(G - 1) - 1e-3f);
    int iu = (int)u;  iu = iu > G - 2 ? G - 2 : iu;
    int iv = (int)v;  iv = iv > G - 2 ? G - 2 : iv;
    const float fu = u - (float)iu;
    const float fv = v - (float)iv;

    float wu[4], wv_[4];
    cr_w(fu, wu);
    cr_w(fv, wv_);

    const int ju0 = iu - 1 < 0 ? 0 : iu - 1;
    const int ju3 = iu + 2 > G - 1 ? G - 1 : iu + 2;
    const int jv0 = iv - 1 < 0 ? 0 : iv - 1;
    const int jv3 = iv + 2 > G - 1 ? G - 1 : iv + 2;
    const int rowsIdx[4] = { jv0 * G, iv * G, (iv + 1) * G, jv3 * G };

    float af = 0.f, at = 0.f, ax = 0.f, axx = 0.f;
    #pragma unroll
    for (int rr = 0; rr < 2; ++rr) {
        const int r = 2 * half + rr;          // this thread's 2 stencil rows
        const int base = rowsIdx[r];
        const float4 g0 = grid[base + ju0];
        const float4 g1 = grid[base + iu];
        const float4 g2 = grid[base + iu + 1];
        const float4 g3 = grid[base + ju3];
        const float rf  = wu[0] * g0.x + wu[1] * g1.x + wu[2] * g2.x + wu[3] * g3.x;
        const float rt  = wu[0] * g0.y + wu[1] * g1.y + wu[2] * g2.y + wu[3] * g3.y;
        const float rx  = wu[0] * g0.z + wu[1] * g1.z + wu[2] * g2.z + wu[3] * g3.z;
        const float rxx = wu[0] * g0.w + wu[1] * g1.w + wu[2] * g2.w + wu[3] * g3.w;
        af  = __builtin_fmaf(wv_[r], rf,  af);
        at  = __builtin_fmaf(wv_[r], rt,  at);
        ax  = __builtin_fmaf(wv_[r], rx,  ax);
        axx = __builtin_fmaf(wv_[r], rxx, axx);
    }
    af  += __shfl_xor(af,  1, 64);
    at  += __shfl_xor(at,  1, 64);
    ax  += __shfl_xor(ax,  1, 64);
    axx += __shfl_xor(axx, 1, 64);

    // fallback: exact direct eval for out-of-range rows (cooperative, rare)
    const bool outl = ((fabsf(xv.x) > XMAX) || (fabsf(xv.y) > XMAX)) && (half == 0);
    unsigned long long mball = __ballot(outl);
    if (mball) {
        const int lane = threadIdx.x & 63;
        const float b2v = b2p[0];
        while (mball) {
            const int l = (int)__ffsll((unsigned long long)mball) - 1;
            mball &= mball - 1;
            const float fx0 = __shfl(xv.x, l, 64);
            const float fx1 = __shfl(xv.y, l, 64);
            float s_f = 0.f, s1 = 0.f, s2 = 0.f, s3 = 0.f, s4 = 0.f;
            for (int k = 0; k < 16; ++k) {
                const int h = lane * 16 + k;
                const float w10 = W1[2 * h], w11 = W1[2 * h + 1];
                const float b1h = b1[h], w2h = w2[h];
                float zs = SCF * __builtin_fmaf(fx0, w10, __builtin_fmaf(fx1, w11, b1h));
                zs = fminf(zs, 40.0f);
                const float e = __builtin_amdgcn_exp2f(zs);
                const float r = __builtin_amdgcn_rcpf(e + 1.0f);
                const float t = __builtin_fmaf(-2.0f, r, 1.0f);
                const float uq = __builtin_fmaf(-r, r, r);
                const float ru = r * uq;
                const float c1 = w10 * w2h, c2 = w11 * w2h, c3 = w11 * c2;
                s_f += t * w2h;
                s1 = __builtin_fmaf(uq, c1, s1);
                s2 = __builtin_fmaf(uq, c2, s2);
                s3 = __builtin_fmaf(uq, c3, s3);
                s4 = __builtin_fmaf(ru, c3, s4);
            }
            #pragma unroll
            for (int m = 32; m >= 1; m >>= 1) {
                s_f += __shfl_xor(s_f, m, 64);
                s1  += __shfl_xor(s1,  m, 64);
                s2  += __shfl_xor(s2,  m, 64);
                s3  += __shfl_xor(s3,  m, 64);
                s4  += __shfl_xor(s4,  m, 64);
            }
            if (lane == l) {
                af  = s_f + b2v;
                at  = 4.0f * s1;
                ax  = 4.0f * s2;
                axx = -8.0f * (s3 - 2.0f * s4);
            }
        }
    }

    if (half == 0) {
        const float x1 = xv.y;
        const float pde = __builtin_fmaf(0.5f * x1, x1, at)
                        + 0.5f * axx
                        + 0.5f * x1 * ax
                        - 0.069444444444444445f * ax * ax;
        out[row] = af;
        out[PN + row] = pde;
    }
}

extern "C" void kernel_launch(void* const* d_in, const int* in_sizes, int n_in,
                              void* d_out, int out_size, void* d_ws, size_t ws_size,
                              hipStream_t stream) {
    const float* x  = (const float*)d_in[0];
    const float* W1 = (const float*)d_in[1];
    const float* b1 = (const float*)d_in[2];
    const float* w2 = (const float*)d_in[3];
    const float* b2 = (const float*)d_in[4];
    float* out = (float*)d_out;
    float4* grid = (float4*)d_ws;      // G*G float4 = 256 KiB

    grid_eval_kernel<<<GPTS / 64, 1024, 0, stream>>>(W1, b1, w2, b2, grid);
    interp_kernel<<<PN * 2 / 256, 256, 0, stream>>>((const float2*)x, grid,
                                                    W1, b1, w2, b2, out);
}

// Round 16
// 21.103 us; speedup vs baseline: 1.4551x; 1.0285x over previous
//
#include <hip/hip_runtime.h>

#define PN 131072
#define PH 1024
#define G 128
#define GPTS (G * G)
#define GLO   (-5.0f)
#define GSTEP (10.0f / 127.0f)
#define GINV  (127.0f / 10.0f)
#define XMAX  4.9f
#define SCF   2.8853900817779268f          // 2*log2(e)
#define SCGSTEP (SCF * GSTEP)
#define SCGLO   (SCF * GLO)

// Catmull-Rom weights for t in [0,1)
static __device__ __forceinline__ void cr_w(float t, float w[4]) {
    w[0] = t * (-0.5f + t * (1.0f - 0.5f * t));
    w[1] = 1.0f + t * t * (-2.5f + 1.5f * t);
    w[2] = t * (0.5f + t * (2.0f - 1.5f * t));
    w[3] = t * t * (-0.5f + 0.5f * t);
}

// ===== K1a: partial table eval — R5-shaped ==================================
// 1024 blocks x 512 thr (8 waves) = 4 blocks/CU -> 8 waves/SIMD.
// block = (point-block pb 0..255) x (h-block hb 0..3, 256 h each).
// Wave owns a wave-uniform 32-h chunk; params stream from GLOBAL memory
// (scalarizable s_load, like R5). lane = grid point. 16 pair-iters/wave.
__global__ __launch_bounds__(512, 8) void eval_part_kernel(const float4* __restrict__ W1f4,
                                                           const float2* __restrict__ b1f2,
                                                           const float2* __restrict__ w2f2,
                                                           float4* __restrict__ part) {
    const int tid  = threadIdx.x;
    const int lane = tid & 63, wv = tid >> 6;          // 8 waves
    const int bid  = blockIdx.x;
    const int pb   = bid & 255;                        // point-block
    const int hb   = bid >> 8;                         // h-block 0..3
    const int chunk = __builtin_amdgcn_readfirstlane(hb * 8 + wv);  // 0..31

    const int p  = pb * 64 + lane;                     // grid point
    const int ix = p & (G - 1);
    const int iy = p >> 7;
    const float x0s = __builtin_fmaf((float)ix, SCGSTEP, SCGLO);   // SC-scaled
    const float x1s = __builtin_fmaf((float)iy, SCGSTEP, SCGLO);

    // per pair j: W1f4[chunk*16+j] = {w10a,w11a,w10b,w11b}
    const float4* __restrict__ W = W1f4 + chunk * 16;
    const float2* __restrict__ B = b1f2 + chunk * 16;
    const float2* __restrict__ V = w2f2 + chunk * 16;

    float aT = 0.f, a1 = 0.f, a2 = 0.f, aD = 0.f;

    #pragma unroll 4
    for (int j = 0; j < 16; ++j) {
        const float4 w = W[j];
        const float2 b = B[j];
        const float2 v = V[j];

        float zsa = __builtin_fmaf(x0s, w.x, __builtin_fmaf(x1s, w.y, b.x * SCF));
        float zsb = __builtin_fmaf(x0s, w.z, __builtin_fmaf(x1s, w.w, b.y * SCF));
        zsa = fminf(zsa, 40.0f);
        zsb = fminf(zsb, 40.0f);
        const float ea = __builtin_amdgcn_exp2f(zsa);       // e^{2z}
        const float eb = __builtin_amdgcn_exp2f(zsb);
        const float da = ea + 1.0f, db = eb + 1.0f;
        const float rab = __builtin_amdgcn_rcpf(da * db);   // shared rcp
        const float ra = rab * db, rb = rab * da;           // 1/(1+e^{2z})
        const float ta = __builtin_fmaf(-2.0f, ra, 1.0f);   // tanh
        const float tb = __builtin_fmaf(-2.0f, rb, 1.0f);
        const float ua = __builtin_fmaf(-ra, ra, ra);       // r - r^2 = q/4
        const float ub = __builtin_fmaf(-rb, rb, rb);
        const float rua = ra * ua, rub = rb * ub;
        const float tua = __builtin_fmaf(-2.0f, rua, ua);   // t*u
        const float tub = __builtin_fmaf(-2.0f, rub, ub);

        const float uw2a = ua * v.x,  uw2b = ub * v.y;      // u*w2
        const float tw2a = tua * v.x, tw2b = tub * v.y;     // t*u*w2

        aT = __builtin_fmaf(ta, v.x, aT);                   // sum t*w2
        aT = __builtin_fmaf(tb, v.y, aT);
        a1 = __builtin_fmaf(uw2a, w.x, a1);                 // * w10
        a1 = __builtin_fmaf(uw2b, w.z, a1);
        a2 = __builtin_fmaf(uw2a, w.y, a2);                 // * w11
        a2 = __builtin_fmaf(uw2b, w.w, a2);
        aD = __builtin_fmaf(tw2a * w.y, w.y, aD);           // * w11^2
        aD = __builtin_fmaf(tw2b * w.w, w.w, aD);
    }

    // reduce the block's 8 waves (R5 pattern)
    __shared__ float4 red[8][64];
    if (wv != 0) red[wv][lane] = make_float4(aT, a1, a2, aD);
    __syncthreads();
    if (wv == 0) {
        float sT = aT, s1 = a1, s2 = a2, sD = aD;
        #pragma unroll
        for (int w = 1; w < 8; ++w) {
            const float4 o = red[w][lane];
            sT += o.x; s1 += o.y; s2 += o.z; sD += o.w;
        }
        part[hb * GPTS + p] = make_float4(sT, s1, s2, sD);
    }
}

// ===== K1b: combine 4 h-block partials, finalize fields =====================
__global__ __launch_bounds__(256) void reduce_kernel(const float4* __restrict__ part,
                                                     const float* __restrict__ b2p,
                                                     float4* __restrict__ grid) {
    const int pt = blockIdx.x * 256 + threadIdx.x;
    float4 s = part[pt];
    #pragma unroll
    for (int k = 1; k < 4; ++k) {
        const float4 o = part[k * GPTS + pt];
        s.x += o.x; s.y += o.y; s.z += o.z; s.w += o.w;
    }
    // f = sum t*w2 + b2 ; df_dt = 4*sum u*w10*w2 ; df_dx = 4*sum u*w11*w2 ;
    // df_dxdx = -8*sum t*u*w11^2*w2
    grid[pt] = make_float4(s.x + b2p[0], 4.0f * s.y, 4.0f * s.z, -8.0f * s.w);
}

// ===== K2: bicubic interp, 2 threads/row + cooperative fallback (R15) =======
__global__ __launch_bounds__(256) void interp_kernel(const float2* __restrict__ x2,
                                                     const float4* __restrict__ grid,
                                                     const float* __restrict__ W1,
                                                     const float* __restrict__ b1,
                                                     const float* __restrict__ w2,
                                                     const float* __restrict__ b2p,
                                                     float* __restrict__ out) {
    const int g = blockIdx.x * 256 + threadIdx.x;
    const int row = g >> 1;
    const int half = g & 1;
    const float2 xv = x2[row];

    float u = (xv.x - GLO) * GINV;
    float v = (xv.y - GLO) * GINV;
    u = fminf(fmaxf(u, 0.0f), (float)(G - 1) - 1e-3f);
    v = fminf(fmaxf(v, 0.0f), (float)(G - 1) - 1e-3f);
    int iu = (int)u;  iu = iu > G - 2 ? G - 2 : iu;
    int iv = (int)v;  iv = iv > G - 2 ? G - 2 : iv;
    const float fu = u - (float)iu;
    const float fv = v - (float)iv;

    float wu[4], wv_[4];
    cr_w(fu, wu);
    cr_w(fv, wv_);

    const int ju0 = iu - 1 < 0 ? 0 : iu - 1;
    const int ju3 = iu + 2 > G - 1 ? G - 1 : iu + 2;
    const int jv0 = iv - 1 < 0 ? 0 : iv - 1;
    const int jv3 = iv + 2 > G - 1 ? G - 1 : iv + 2;
    const int rowsIdx[4] = { jv0 * G, iv * G, (iv + 1) * G, jv3 * G };

    float af = 0.f, at = 0.f, ax = 0.f, axx = 0.f;
    #pragma unroll
    for (int rr = 0; rr < 2; ++rr) {
        const int r = 2 * half + rr;
        const int base = rowsIdx[r];
        const float4 g0 = grid[base + ju0];
        const float4 g1 = grid[base + iu];
        const float4 g2 = grid[base + iu + 1];
        const float4 g3 = grid[base + ju3];
        const float rf  = wu[0] * g0.x + wu[1] * g1.x + wu[2] * g2.x + wu[3] * g3.x;
        const float rt  = wu[0] * g0.y + wu[1] * g1.y + wu[2] * g2.y + wu[3] * g3.y;
        const float rx  = wu[0] * g0.z + wu[1] * g1.z + wu[2] * g2.z + wu[3] * g3.z;
        const float rxx = wu[0] * g0.w + wu[1] * g1.w + wu[2] * g2.w + wu[3] * g3.w;
        af  = __builtin_fmaf(wv_[r], rf,  af);
        at  = __builtin_fmaf(wv_[r], rt,  at);
        ax  = __builtin_fmaf(wv_[r], rx,  ax);
        axx = __builtin_fmaf(wv_[r], rxx, axx);
    }
    af  += __shfl_xor(af,  1, 64);
    at  += __shfl_xor(at,  1, 64);
    ax  += __shfl_xor(ax,  1, 64);
    axx += __shfl_xor(axx, 1, 64);

    const bool outl = ((fabsf(xv.x) > XMAX) || (fabsf(xv.y) > XMAX)) && (half == 0);
    unsigned long long mball = __ballot(outl);
    if (mball) {
        const int lane = threadIdx.x & 63;
        const float b2v = b2p[0];
        while (mball) {
            const int l = (int)__ffsll((unsigned long long)mball) - 1;
            mball &= mball - 1;
            const float fx0 = __shfl(xv.x, l, 64);
            const float fx1 = __shfl(xv.y, l, 64);
            float s_f = 0.f, s1 = 0.f, s2 = 0.f, s3 = 0.f, s4 = 0.f;
            for (int k = 0; k < 16; ++k) {
                const int h = lane * 16 + k;
                const float w10 = W1[2 * h], w11 = W1[2 * h + 1];
                const float b1h = b1[h], w2h = w2[h];
                float zs = SCF * __builtin_fmaf(fx0, w10, __builtin_fmaf(fx1, w11, b1h));
                zs = fminf(zs, 40.0f);
                const float e = __builtin_amdgcn_exp2f(zs);
                const float r = __builtin_amdgcn_rcpf(e + 1.0f);
                const float t = __builtin_fmaf(-2.0f, r, 1.0f);
                const float uq = __builtin_fmaf(-r, r, r);
                const float ru = r * uq;
                const float c1 = w10 * w2h, c2 = w11 * w2h, c3 = w11 * c2;
                s_f += t * w2h;
                s1 = __builtin_fmaf(uq, c1, s1);
                s2 = __builtin_fmaf(uq, c2, s2);
                s3 = __builtin_fmaf(uq, c3, s3);
                s4 = __builtin_fmaf(ru, c3, s4);
            }
            #pragma unroll
            for (int m = 32; m >= 1; m >>= 1) {
                s_f += __shfl_xor(s_f, m, 64);
                s1  += __shfl_xor(s1,  m, 64);
                s2  += __shfl_xor(s2,  m, 64);
                s3  += __shfl_xor(s3,  m, 64);
                s4  += __shfl_xor(s4,  m, 64);
            }
            if (lane == l) {
                af  = s_f + b2v;
                at  = 4.0f * s1;
                ax  = 4.0f * s2;
                axx = -8.0f * (s3 - 2.0f * s4);
            }
        }
    }

    if (half == 0) {
        const float x1 = xv.y;
        const float pde = __builtin_fmaf(0.5f * x1, x1, at)
                        + 0.5f * axx
                        + 0.5f * x1 * ax
                        - 0.069444444444444445f * ax * ax;
        out[row] = af;
        out[PN + row] = pde;
    }
}

extern "C" void kernel_launch(void* const* d_in, const int* in_sizes, int n_in,
                              void* d_out, int out_size, void* d_ws, size_t ws_size,
                              hipStream_t stream) {
    const float* x  = (const float*)d_in[0];
    const float* W1 = (const float*)d_in[1];
    const float* b1 = (const float*)d_in[2];
    const float* w2 = (const float*)d_in[3];
    const float* b2 = (const float*)d_in[4];
    float* out = (float*)d_out;

    float4* grid = (float4*)d_ws;                 // GPTS float4 = 256 KiB
    float4* part = (float4*)d_ws + GPTS;          // 4*GPTS float4 = 1 MiB

    eval_part_kernel<<<1024, 512, 0, stream>>>((const float4*)W1, (const float2*)b1,
                                               (const float2*)w2, part);
    reduce_kernel<<<GPTS / 256, 256, 0, stream>>>(part, b2, grid);
    interp_kernel<<<PN * 2 / 256, 256, 0, stream>>>((const float2*)x, grid,
                                                    W1, b1, w2, b2, out);
}